// Round 1
// baseline (103.993 us; speedup 1.0000x reference)
//
#include <hip/hip_runtime.h>

// MeanAggregator: out[b,:] = mean_{s<25} emb[neigh[b,s], :], emb fp32 [100000,128].
// v2: one row per wave64, scalar (SGPR) gather addressing.
//   - 64 lanes x float2 cover one 128-dim row (512 B).
//   - 25 indices fetched with ONE coalesced load (lanes 0..24), then moved to
//     SGPRs via v_readlane -> each gather is global_load_dwordx2 with saddr:
//     scalar base (SALU-computed) + shared voffset VGPR. No ds_bpermute, no
//     per-lane 64-bit address math, minimal VGPR pressure.
//   - All 25 loads per wave are independent -> deep MLP; __launch_bounds__(256,8)
//     pins VGPRs <= 64 for full 8 waves/SIMD occupancy.
//   - Output stored nontemporal: 8.4 MB of write-once data should not evict
//     gather lines from the 4 MB/XCD L2.

constexpr int EMB_DIM         = 128;
constexpr int NUM_SAMPLE      = 25;
constexpr int WAVES_PER_BLOCK = 4;   // 256 threads, 1 row per wave64

typedef float vfloat2 __attribute__((ext_vector_type(2)));

__global__ __launch_bounds__(256, 8)
void mean_agg_kernel(const float* __restrict__ emb,
                     const int*   __restrict__ neigh,
                     float*       __restrict__ out,
                     int batch)
{
    const int wave = threadIdx.x >> 6;          // wave id within block
    const int lane = threadIdx.x & 63;          // lane within wave64
    const int row  = blockIdx.x * WAVES_PER_BLOCK + wave;
    if (row >= batch) return;

    const int* nrow = neigh + (size_t)row * NUM_SAMPLE;

    // One coalesced index load per wave: lanes 0..24 each grab one index.
    int my_idx = (lane < NUM_SAMPLE) ? nrow[lane] : 0;

    // Two accumulators to halve the serial FP-add chain.
    float ax0 = 0.f, ay0 = 0.f;
    float ax1 = 0.f, ay1 = 0.f;

    #pragma unroll
    for (int s = 0; s < NUM_SAMPLE; ++s) {
        // Wave-uniform index -> SGPR. Enables saddr-form global loads.
        const int idx = __builtin_amdgcn_readlane(my_idx, s);
        const vfloat2* src =
            reinterpret_cast<const vfloat2*>(emb + (size_t)idx * EMB_DIM);
        vfloat2 v = src[lane];                  // 64 lanes x 8 B = 512 B row read
        if (s & 1) { ax1 += v.x; ay1 += v.y; }
        else       { ax0 += v.x; ay0 += v.y; }
    }

    constexpr float inv = 1.0f / NUM_SAMPLE;
    vfloat2 r;
    r.x = (ax0 + ax1) * inv;
    r.y = (ay0 + ay1) * inv;

    vfloat2* orow = reinterpret_cast<vfloat2*>(out + (size_t)row * EMB_DIM);
    __builtin_nontemporal_store(r, orow + lane);
}

extern "C" void kernel_launch(void* const* d_in, const int* in_sizes, int n_in,
                              void* d_out, int out_size, void* d_ws, size_t ws_size,
                              hipStream_t stream) {
    const float* emb   = (const float*)d_in[0];
    const int*   neigh = (const int*)d_in[1];
    float*       out   = (float*)d_out;

    const int batch = in_sizes[1] / NUM_SAMPLE;   // 16384
    const int rows_per_block = WAVES_PER_BLOCK;
    const int grid = (batch + rows_per_block - 1) / rows_per_block;

    mean_agg_kernel<<<grid, 256, 0, stream>>>(emb, neigh, out, batch);
}